// Round 12
// baseline (320.571 us; speedup 1.0000x reference)
//
#include <hip/hip_runtime.h>

typedef unsigned short u16;
typedef unsigned int u32;
typedef __attribute__((ext_vector_type(2))) u32 u32x2;
typedef __attribute__((ext_vector_type(4))) u32 u32x4;
typedef __attribute__((ext_vector_type(4))) float f32x4;
typedef __attribute__((ext_vector_type(8))) short s16x8;

#define DEV __device__ __forceinline__

DEV float bflo(u32 u){ union{u32 i; float f;} c; c.i = u << 16; return c.f; }
DEV float bfhi(u32 u){ union{u32 i; float f;} c; c.i = u & 0xffff0000u; return c.f; }
DEV u16 f2b(float f){
  union{float f; u32 u;} c; c.f = f;
  u32 u = c.u;
  u32 r = (u + 0x7fffu + ((u >> 16) & 1u)) >> 16;
  return (u16)r;
}
DEV float fsilu(float v){ return v / (1.f + __expf(-v)); }

constexpr int Bn = 32, Cin = 64, H = 56, Wd = 56, HID = 384, CO = 64;
constexpr int HW = H * Wd;            // 3136
constexpr float EPS = 1e-5f;

constexpr int XROW = 72 * 64;         // sB row pitch: [slot 72][ic 64] bf16
// wt geometry: [octile 3][tap 9][ocl 128][64], octet o at phys o^(ocl&7)
constexpr int WTAP = 128 * 64;
constexpr int WOCT = 9 * WTAP;

// ---------------------------------------------------------------------------
// P1: pack expand weights -> wt (swizzled) + BN1/BN3 scale-shift (block 864).
// ---------------------------------------------------------------------------
__global__ __launch_bounds__(256) void k_prep_wbn(
    const float* __restrict__ w,
    const float* __restrict__ g1, const float* __restrict__ b1,
    const float* __restrict__ m1, const float* __restrict__ v1,
    const float* __restrict__ g3, const float* __restrict__ b3,
    const float* __restrict__ m3, const float* __restrict__ v3,
    u16* __restrict__ wt,
    float* __restrict__ sc1, float* __restrict__ sh1,
    float* __restrict__ sc3, float* __restrict__ sh3)
{
  const int blk = blockIdx.x;
  if (blk < 864) {
    int t = blk * 256 + threadIdx.x;             // < 3*73728
    int octile = t / WOCT, r = t - octile * WOCT;
    int tap = r / WTAP, r2 = r - tap * WTAP;
    int ocl = r2 >> 6, col = r2 & 63;
    int physo = col >> 3, j = col & 7;
    int olog = physo ^ (ocl & 7);
    int ic = olog * 8 + j;
    int oc = octile * 128 + ocl;
    wt[t] = f2b(w[(oc * Cin + ic) * 9 + tap]);
  } else {
    for (int t = threadIdx.x; t < HID; t += 256) {
      float sc = g1[t] * rsqrtf(v1[t] + EPS);
      sc1[t] = sc;
      sh1[t] = b1[t] - m1[t] * sc;
    }
    if (threadIdx.x < CO) {
      int t = threadIdx.x;
      float sc = g3[t] * rsqrtf(v3[t] + EPS);
      sc3[t] = sc;
      sh3[t] = b3[t] - m3[t] * sc;
    }
  }
}

// ---------------------------------------------------------------------------
// K1: expand conv MFMA shift-GEMM. x staged once per block; octile loop
// inside (3x MFMA per staging). grid (28 ypair, bc b), 256 thr.
// ---------------------------------------------------------------------------
__global__ __launch_bounds__(256, 2) void k_expand_mfma(
    const float* __restrict__ x, const u16* __restrict__ wt,
    const float* __restrict__ sc1, const float* __restrict__ sh1,
    u16* __restrict__ h, int b0)
{
  __shared__ u16 sB[4 * XROW];      // 36,864 B
  __shared__ u16 sA[WTAP];          // 16,384 B
  const int tid = threadIdx.x;
  const int ypair = blockIdx.x, b = blockIdx.y;
  const int gb = b0 + b;
  const int y0 = ypair * 2;
  const int wave = tid >> 6, ln = tid & 63;
  const int wm = wave >> 1, wn = wave & 1;
  const int lane15 = ln & 15, quad = ln >> 4;

  // ---- zero sB (covers pad slots 0,57..71 and OOB rows)
  {
    u32x4 z = {0, 0, 0, 0};
    #pragma unroll
    for (int i = 0; i < 18; ++i)
      *(u32x4*)&sB[(i * 256 + tid) * 8] = z;
  }
  __syncthreads();
  // ---- stage 4 rows from x: wave = 14-px span, lane = ic
  {
    const int ic = tid & 63, xq = tid >> 6;
    #pragma unroll
    for (int r = 0; r < 4; ++r) {
      const int y = y0 + r - 1;
      if (y >= 0 && y < H) {
        const float* xp = x + ((size_t)(gb * Cin + ic) * H + y) * Wd + xq * 14;
        float vals[14];
        #pragma unroll
        for (int t = 0; t < 14; ++t) vals[t] = xp[t];
        u16* rowp = &sB[r * XROW];
        #pragma unroll
        for (int t = 0; t < 14; ++t) {
          int slot = xq * 14 + t + 1;
          int pos = slot * 64 + (((ic >> 3) ^ (slot & 7)) << 3) + (ic & 7);
          rowp[pos] = f2b(vals[t]);
        }
      }
    }
  }
  // (first tap's __syncthreads guards sB)

  const int y = y0 + wn;

  for (int octile = 0; octile < 3; ++octile) {
    f32x4 acc[4][4];
    #pragma unroll
    for (int ms = 0; ms < 4; ++ms)
      #pragma unroll
      for (int ns = 0; ns < 4; ++ns) acc[ms][ns] = (f32x4){0.f, 0.f, 0.f, 0.f};

    const u16* wsrc = wt + (size_t)octile * WOCT;
    for (int tap = 0; tap < 9; ++tap) {
      __syncthreads();
      #pragma unroll
      for (int it = 0; it < 4; ++it) {
        int i = it * 256 + tid;
        *(u32x4*)&sA[i * 8] = *(const u32x4*)&wsrc[tap * WTAP + i * 8];
      }
      __syncthreads();
      const int dy = tap / 3, dx = tap - dy * 3;
      #pragma unroll
      for (int kk = 0; kk < 2; ++kk) {
        s16x8 af[4], bf[4];
        #pragma unroll
        for (int ms = 0; ms < 4; ++ms) {
          int ocl = wm * 64 + ms * 16 + lane15;
          int po = (kk * 4 + quad) ^ (ocl & 7);
          af[ms] = *(const s16x8*)&sA[ocl * 64 + po * 8];
        }
        #pragma unroll
        for (int ns = 0; ns < 4; ++ns) {
          int row = wn + dy;
          int slot = ns * 16 + lane15 + dx;
          int po = (kk * 4 + quad) ^ (slot & 7);
          bf[ns] = *(const s16x8*)&sB[(row * 72 + slot) * 64 + po * 8];
        }
        #pragma unroll
        for (int ms = 0; ms < 4; ++ms)
          #pragma unroll
          for (int ns = 0; ns < 4; ++ns)
            acc[ms][ns] = __builtin_amdgcn_mfma_f32_16x16x32_bf16(
                af[ms], bf[ns], acc[ms][ns], 0, 0, 0);
      }
    }

    #pragma unroll
    for (int ms = 0; ms < 4; ++ms) {
      int oc0 = octile * 128 + wm * 64 + ms * 16 + quad * 4;
      f32x4 sc = *(const f32x4*)&sc1[oc0];
      f32x4 sh = *(const f32x4*)&sh1[oc0];
      float scr[4] = {sc.x, sc.y, sc.z, sc.w};
      float shr[4] = {sh.x, sh.y, sh.z, sh.w};
      #pragma unroll
      for (int ns = 0; ns < 4; ++ns) {
        int xg = ns * 16 + lane15;
        if (xg < Wd) {
          float av[4] = {acc[ms][ns].x, acc[ms][ns].y, acc[ms][ns].z, acc[ms][ns].w};
          #pragma unroll
          for (int r = 0; r < 4; ++r) {
            float val = fsilu(av[r] * scr[r] + shr[r]);
            h[((size_t)(b * HID + oc0 + r) * H + y) * Wd + xg] = f2b(val);
          }
        }
      }
    }
  }
}

// ---------------------------------------------------------------------------
// K2: depthwise 3x3 + BN2 + SiLU -> d (bf16) + per-(b,c) mean.
// v3: word-per-thread (2 px), 28 words/row so words never straddle rows.
// All 9 loads + 1 store are lane-stride-1 -> fully coalesced.
// ---------------------------------------------------------------------------
__global__ __launch_bounds__(256) void k_dw(
    const u16* __restrict__ h, const float* __restrict__ wdw,
    const float* __restrict__ g2, const float* __restrict__ b2,
    const float* __restrict__ m2, const float* __restrict__ v2,
    u16* __restrict__ d, float* __restrict__ mean)
{
  __shared__ float red[4];
  const int tid = threadIdx.x;
  const int c = blockIdx.x, b = blockIdx.y;
  const u32* hp32 = (const u32*)(h + (size_t)(b * HID + c) * HW);
  u32* dp32 = (u32*)(d + (size_t)(b * HID + c) * HW);

  float wv[9];
  #pragma unroll
  for (int t = 0; t < 9; ++t) wv[t] = wdw[c * 9 + t];
  const float sc = g2[c] * rsqrtf(v2[c] + EPS);
  const float sh = b2[c] - m2[c] * sc;

  float lsum = 0.f;
  for (int w = tid; w < 1568; w += 256) {        // 1568 words = 56 rows x 28
    const int wrow = w / 28, wcol = w - wrow * 28;
    float lf[3], m0[3], m1[3], rt[3];
    #pragma unroll
    for (int r3 = 0; r3 < 3; ++r3) {
      int rr = wrow + r3 - 1;
      bool ok = (rr >= 0) && (rr < 56);
      const u32* rp = hp32 + rr * 28;
      lf[r3] = (ok && wcol > 0)  ? bfhi(rp[wcol - 1]) : 0.f;
      u32 mid = ok ? rp[wcol] : 0u;
      m0[r3] = bflo(mid);
      m1[r3] = bfhi(mid);
      rt[r3] = (ok && wcol < 27) ? bflo(rp[wcol + 1]) : 0.f;
    }
    float s0 = 0.f, s1 = 0.f;
    #pragma unroll
    for (int r3 = 0; r3 < 3; ++r3) {
      s0 += lf[r3] * wv[r3 * 3] + m0[r3] * wv[r3 * 3 + 1] + m1[r3] * wv[r3 * 3 + 2];
      s1 += m0[r3] * wv[r3 * 3] + m1[r3] * wv[r3 * 3 + 1] + rt[r3] * wv[r3 * 3 + 2];
    }
    float o0 = fsilu(s0 * sc + sh);
    float o1 = fsilu(s1 * sc + sh);
    lsum += o0 + o1;
    dp32[w] = (u32)f2b(o0) | ((u32)f2b(o1) << 16);
  }

  #pragma unroll
  for (int off = 32; off > 0; off >>= 1) lsum += __shfl_down(lsum, off);
  if ((tid & 63) == 0) red[tid >> 6] = lsum;
  __syncthreads();
  if (tid == 0)
    mean[b * HID + c] = (red[0] + red[1] + red[2] + red[3]) * (1.f / 3136.f);
}

// ---------------------------------------------------------------------------
// K3: SE + A'-fold fused. grid bc, block 256.
// ---------------------------------------------------------------------------
__global__ __launch_bounds__(256) void k_se_a(
    const float* __restrict__ mean, const float* __restrict__ w1,
    const float* __restrict__ w2, const float* __restrict__ wpw,
    const float* __restrict__ sc3, u16* __restrict__ afold)
{
  __shared__ float sm[HID];
  __shared__ float ps[16 * 17];
  __shared__ float s1[16];
  __shared__ float sf[HID];
  const int b = blockIdx.x, tid = threadIdx.x;
  for (int c = tid; c < HID; c += 256) sm[c] = mean[b * HID + c];
  __syncthreads();
  int r = tid >> 4, j = tid & 15;
  float p = 0.f;
  for (int c = j; c < HID; c += 16) p += sm[c] * w1[r * HID + c];
  ps[r * 17 + j] = p;
  __syncthreads();
  if (tid < 16) {
    float s = 0.f;
    #pragma unroll
    for (int q = 0; q < 16; ++q) s += ps[tid * 17 + q];
    s1[tid] = fsilu(s);
  }
  __syncthreads();
  for (int c = tid; c < HID; c += 256) {
    float s = 0.f;
    #pragma unroll
    for (int q = 0; q < 16; ++q) s += s1[q] * w2[c * 16 + q];
    sf[c] = 1.f / (1.f + __expf(-s));
  }
  __syncthreads();
  for (int i = tid; i < 6144; i += 256) {
    int e = i * 4, co = e / 384, k = e - co * 384;
    f32x4 wv = *(const f32x4*)&wpw[e];
    float s3 = sc3[co];
    u32x2 pk;
    pk.x = (u32)f2b(wv.x * sf[k] * s3)     | ((u32)f2b(wv.y * sf[k+1] * s3) << 16);
    pk.y = (u32)f2b(wv.z * sf[k+2] * s3)   | ((u32)f2b(wv.w * sf[k+3] * s3) << 16);
    *(u32x2*)&afold[(size_t)b * 24576 + e] = pk;
  }
}

// ---------------------------------------------------------------------------
// K4: pointwise MFMA GEMM — per-wave private B-staging, no K-loop barriers.
// grid (25 px-tiles of 128, bc b), 256 thr.
// ---------------------------------------------------------------------------
constexpr int PWP = 392;

__global__ __launch_bounds__(256, 2) void k_pw_mfma(
    const u16* __restrict__ d, const u16* __restrict__ afold,
    const float* __restrict__ sh3,
    const float* __restrict__ x, float* __restrict__ out, int b0)
{
  __shared__ u16 sAw[64 * PWP];     // 50,176 B
  __shared__ u32 dtw[4 * 512];      // 8,192 B
  const int tid = threadIdx.x;
  const int b = blockIdx.y, gb = b0 + b;
  const int p0 = blockIdx.x * 128;
  const int wave = tid >> 6, ln = tid & 63;
  const int lane15 = ln & 15, quad = ln >> 4;

  {
    const u16* ab = afold + (size_t)b * 24576;
    #pragma unroll
    for (int i = tid; i < 3072; i += 256) {
      int e = i * 8, co = e / 384, k = e - co * 384;
      *(u32x4*)&sAw[co * PWP + k] = *(const u32x4*)&ab[e];
    }
  }
  __syncthreads();

  f32x4 acc[4][2];
  #pragma unroll
  for (int ms = 0; ms < 4; ++ms)
    #pragma unroll
    for (int ns = 0; ns < 2; ++ns) acc[ms][ns] = (f32x4){0.f, 0.f, 0.f, 0.f};

  const int cpair = ln >> 2;
  const int pxo = (ln & 3) * 8;
  const int pbase = p0 + wave * 32;
  u32* mydt = &dtw[wave * 512];
  const bool ld_ok = (pbase + pxo + 8 <= HW);

  for (int ks = 0; ks < 12; ++ks) {
    const int k0 = ks * 32;
    u32x4 r0 = {0,0,0,0}, r1 = {0,0,0,0};
    if (ld_ok) {
      int c = k0 + 2 * cpair;
      const u16* dpp = d + (size_t)(b * HID + c) * HW + pbase + pxo;
      r0 = *(const u32x4*)dpp;
      r1 = *(const u32x4*)(dpp + HW);
    }
    u32* w0 = &mydt[pxo * 16 + cpair];
    w0[0 * 16] = (r0.x & 0xffffu) | (r1.x << 16);
    w0[1 * 16] = (r0.x >> 16)     | (r1.x & 0xffff0000u);
    w0[2 * 16] = (r0.y & 0xffffu) | (r1.y << 16);
    w0[3 * 16] = (r0.y >> 16)     | (r1.y & 0xffff0000u);
    w0[4 * 16] = (r0.z & 0xffffu) | (r1.z << 16);
    w0[5 * 16] = (r0.z >> 16)     | (r1.z & 0xffff0000u);
    w0[6 * 16] = (r0.w & 0xffffu) | (r1.w << 16);
    w0[7 * 16] = (r0.w >> 16)     | (r1.w & 0xffff0000u);
    s16x8 af[4], bf[2];
    #pragma unroll
    for (int ms = 0; ms < 4; ++ms) {
      int ocl = ms * 16 + lane15;
      af[ms] = *(const s16x8*)&sAw[ocl * PWP + k0 + quad * 8];
    }
    #pragma unroll
    for (int ns = 0; ns < 2; ++ns) {
      int pxl = ns * 16 + lane15;
      bf[ns] = *(const s16x8*)((const u16*)mydt + pxl * 32 + quad * 8);
    }
    #pragma unroll
    for (int ms = 0; ms < 4; ++ms)
      #pragma unroll
      for (int ns = 0; ns < 2; ++ns)
        acc[ms][ns] = __builtin_amdgcn_mfma_f32_16x16x32_bf16(
            af[ms], bf[ns], acc[ms][ns], 0, 0, 0);
  }

  #pragma unroll
  for (int ns = 0; ns < 2; ++ns) {
    int p = pbase + ns * 16 + lane15;
    if (p < HW) {
      #pragma unroll
      for (int ms = 0; ms < 4; ++ms) {
        int co0 = ms * 16 + quad * 4;
        float av[4] = {acc[ms][ns].x, acc[ms][ns].y, acc[ms][ns].z, acc[ms][ns].w};
        #pragma unroll
        for (int r = 0; r < 4; ++r) {
          size_t idx = (size_t)(gb * CO + co0 + r) * HW + p;
          out[idx] = av[r] + sh3[co0 + r] + x[idx];
        }
      }
    }
  }
}

// ---------------------------------------------------------------------------
extern "C" void kernel_launch(void* const* d_in, const int* in_sizes, int n_in,
                              void* d_out, int out_size, void* d_ws, size_t ws_size,
                              hipStream_t stream)
{
  (void)in_sizes; (void)n_in; (void)out_size;
  const float* x     = (const float*)d_in[0];
  const float* w_exp = (const float*)d_in[1];
  const float* g1 = (const float*)d_in[2];
  const float* b1 = (const float*)d_in[3];
  const float* m1 = (const float*)d_in[4];
  const float* v1 = (const float*)d_in[5];
  const float* w_dw = (const float*)d_in[6];
  const float* g2 = (const float*)d_in[7];
  const float* b2 = (const float*)d_in[8];
  const float* m2 = (const float*)d_in[9];
  const float* v2 = (const float*)d_in[10];
  const float* w_se1 = (const float*)d_in[11];
  const float* w_se2 = (const float*)d_in[12];
  const float* w_pw  = (const float*)d_in[13];
  const float* g3 = (const float*)d_in[14];
  const float* b3 = (const float*)d_in[15];
  const float* m3 = (const float*)d_in[16];
  const float* v3 = (const float*)d_in[17];

  const size_t perB = (size_t)HID * HW * 2 * 2 + 24576 * 2 + HID * 4;
  const size_t fixed = 221184 * 2 + HID * 8 + CO * 8;
  int bc = Bn;
  while (bc > 1 && fixed + (size_t)bc * perB > ws_size) bc >>= 1;

  u16* wt = (u16*)d_ws;
  float* sc1 = (float*)(wt + 221184);
  float* sh1 = sc1 + HID;
  float* sc3 = sh1 + HID;
  float* sh3 = sc3 + CO;
  u16* h  = (u16*)(sh3 + CO);
  u16* dd = h + (size_t)bc * HID * HW;
  u16* afold = dd + (size_t)bc * HID * HW;
  float* mean = (float*)(afold + (size_t)bc * 24576);

  k_prep_wbn<<<865, 256, 0, stream>>>(w_exp, g1, b1, m1, v1, g3, b3, m3, v3,
                                      wt, sc1, sh1, sc3, sh3);

  for (int b0 = 0; b0 < Bn; b0 += bc) {
    k_expand_mfma<<<dim3(28, bc), 256, 0, stream>>>(x, wt, sc1, sh1, h, b0);
    k_dw<<<dim3(HID, bc), 256, 0, stream>>>(h, w_dw, g2, b2, m2, v2, dd, mean);
    k_se_a<<<bc, 256, 0, stream>>>(mean, w_se1, w_se2, w_pw, sc3, afold);
    k_pw_mfma<<<dim3(25, bc), 256, 0, stream>>>(dd, afold, sh3,
                                                x, (float*)d_out, b0);
  }
}

// Round 13
// 288.330 us; speedup vs baseline: 1.1118x; 1.1118x over previous
//
#include <hip/hip_runtime.h>

typedef unsigned short u16;
typedef unsigned int u32;
typedef __attribute__((ext_vector_type(2))) u32 u32x2;
typedef __attribute__((ext_vector_type(4))) u32 u32x4;
typedef __attribute__((ext_vector_type(4))) float f32x4;
typedef __attribute__((ext_vector_type(8))) short s16x8;

#define DEV __device__ __forceinline__

DEV float bflo(u32 u){ union{u32 i; float f;} c; c.i = u << 16; return c.f; }
DEV float bfhi(u32 u){ union{u32 i; float f;} c; c.i = u & 0xffff0000u; return c.f; }
DEV u16 f2b(float f){
  union{float f; u32 u;} c; c.f = f;
  u32 u = c.u;
  u32 r = (u + 0x7fffu + ((u >> 16) & 1u)) >> 16;
  return (u16)r;
}
DEV float fsilu(float v){ return v / (1.f + __expf(-v)); }

constexpr int Bn = 32, Cin = 64, H = 56, Wd = 56, HID = 384, CO = 64;
constexpr int HW = H * Wd;            // 3136
constexpr float EPS = 1e-5f;

constexpr int XROW = 72 * 64;         // sB row pitch: [slot 72][ic 64] bf16
// wt geometry: [octile 3][tap 9][ocl 128][64], octet o at phys o^(ocl&7)
constexpr int WTAP = 128 * 64;
constexpr int WOCT = 9 * WTAP;

// ---------------------------------------------------------------------------
// P1: pack expand weights -> wt (swizzled) + BN1/BN3 scale-shift (block 864).
// ---------------------------------------------------------------------------
__global__ __launch_bounds__(256) void k_prep_wbn(
    const float* __restrict__ w,
    const float* __restrict__ g1, const float* __restrict__ b1,
    const float* __restrict__ m1, const float* __restrict__ v1,
    const float* __restrict__ g3, const float* __restrict__ b3,
    const float* __restrict__ m3, const float* __restrict__ v3,
    u16* __restrict__ wt,
    float* __restrict__ sc1, float* __restrict__ sh1,
    float* __restrict__ sc3, float* __restrict__ sh3)
{
  const int blk = blockIdx.x;
  if (blk < 864) {
    int t = blk * 256 + threadIdx.x;             // < 3*73728
    int octile = t / WOCT, r = t - octile * WOCT;
    int tap = r / WTAP, r2 = r - tap * WTAP;
    int ocl = r2 >> 6, col = r2 & 63;
    int physo = col >> 3, j = col & 7;
    int olog = physo ^ (ocl & 7);
    int ic = olog * 8 + j;
    int oc = octile * 128 + ocl;
    wt[t] = f2b(w[(oc * Cin + ic) * 9 + tap]);
  } else {
    for (int t = threadIdx.x; t < HID; t += 256) {
      float sc = g1[t] * rsqrtf(v1[t] + EPS);
      sc1[t] = sc;
      sh1[t] = b1[t] - m1[t] * sc;
    }
    if (threadIdx.x < CO) {
      int t = threadIdx.x;
      float sc = g3[t] * rsqrtf(v3[t] + EPS);
      sc3[t] = sc;
      sh3[t] = b3[t] - m3[t] * sc;
    }
  }
}

// ---------------------------------------------------------------------------
// K1: expand conv MFMA shift-GEMM (r12 merged version: x staged once,
// octile loop inside). grid (28 ypair, bc b), 256 thr.
// ---------------------------------------------------------------------------
__global__ __launch_bounds__(256, 2) void k_expand_mfma(
    const float* __restrict__ x, const u16* __restrict__ wt,
    const float* __restrict__ sc1, const float* __restrict__ sh1,
    u16* __restrict__ h, int b0)
{
  __shared__ u16 sB[4 * XROW];      // 36,864 B
  __shared__ u16 sA[WTAP];          // 16,384 B
  const int tid = threadIdx.x;
  const int ypair = blockIdx.x, b = blockIdx.y;
  const int gb = b0 + b;
  const int y0 = ypair * 2;
  const int wave = tid >> 6, ln = tid & 63;
  const int wm = wave >> 1, wn = wave & 1;
  const int lane15 = ln & 15, quad = ln >> 4;

  {
    u32x4 z = {0, 0, 0, 0};
    #pragma unroll
    for (int i = 0; i < 18; ++i)
      *(u32x4*)&sB[(i * 256 + tid) * 8] = z;
  }
  __syncthreads();
  {
    const int ic = tid & 63, xq = tid >> 6;
    #pragma unroll
    for (int r = 0; r < 4; ++r) {
      const int y = y0 + r - 1;
      if (y >= 0 && y < H) {
        const float* xp = x + ((size_t)(gb * Cin + ic) * H + y) * Wd + xq * 14;
        float vals[14];
        #pragma unroll
        for (int t = 0; t < 14; ++t) vals[t] = xp[t];
        u16* rowp = &sB[r * XROW];
        #pragma unroll
        for (int t = 0; t < 14; ++t) {
          int slot = xq * 14 + t + 1;
          int pos = slot * 64 + (((ic >> 3) ^ (slot & 7)) << 3) + (ic & 7);
          rowp[pos] = f2b(vals[t]);
        }
      }
    }
  }

  const int y = y0 + wn;

  for (int octile = 0; octile < 3; ++octile) {
    f32x4 acc[4][4];
    #pragma unroll
    for (int ms = 0; ms < 4; ++ms)
      #pragma unroll
      for (int ns = 0; ns < 4; ++ns) acc[ms][ns] = (f32x4){0.f, 0.f, 0.f, 0.f};

    const u16* wsrc = wt + (size_t)octile * WOCT;
    for (int tap = 0; tap < 9; ++tap) {
      __syncthreads();
      #pragma unroll
      for (int it = 0; it < 4; ++it) {
        int i = it * 256 + tid;
        *(u32x4*)&sA[i * 8] = *(const u32x4*)&wsrc[tap * WTAP + i * 8];
      }
      __syncthreads();
      const int dy = tap / 3, dx = tap - dy * 3;
      #pragma unroll
      for (int kk = 0; kk < 2; ++kk) {
        s16x8 af[4], bf[4];
        #pragma unroll
        for (int ms = 0; ms < 4; ++ms) {
          int ocl = wm * 64 + ms * 16 + lane15;
          int po = (kk * 4 + quad) ^ (ocl & 7);
          af[ms] = *(const s16x8*)&sA[ocl * 64 + po * 8];
        }
        #pragma unroll
        for (int ns = 0; ns < 4; ++ns) {
          int row = wn + dy;
          int slot = ns * 16 + lane15 + dx;
          int po = (kk * 4 + quad) ^ (slot & 7);
          bf[ns] = *(const s16x8*)&sB[(row * 72 + slot) * 64 + po * 8];
        }
        #pragma unroll
        for (int ms = 0; ms < 4; ++ms)
          #pragma unroll
          for (int ns = 0; ns < 4; ++ns)
            acc[ms][ns] = __builtin_amdgcn_mfma_f32_16x16x32_bf16(
                af[ms], bf[ns], acc[ms][ns], 0, 0, 0);
      }
    }

    #pragma unroll
    for (int ms = 0; ms < 4; ++ms) {
      int oc0 = octile * 128 + wm * 64 + ms * 16 + quad * 4;
      f32x4 sc = *(const f32x4*)&sc1[oc0];
      f32x4 sh = *(const f32x4*)&sh1[oc0];
      float scr[4] = {sc.x, sc.y, sc.z, sc.w};
      float shr[4] = {sh.x, sh.y, sh.z, sh.w};
      #pragma unroll
      for (int ns = 0; ns < 4; ++ns) {
        int xg = ns * 16 + lane15;
        if (xg < Wd) {
          float av[4] = {acc[ms][ns].x, acc[ms][ns].y, acc[ms][ns].z, acc[ms][ns].w};
          #pragma unroll
          for (int r = 0; r < 4; ++r) {
            float val = fsilu(av[r] * scr[r] + shr[r]);
            h[((size_t)(b * HID + oc0 + r) * H + y) * Wd + xg] = f2b(val);
          }
        }
      }
    }
  }
}

// ---------------------------------------------------------------------------
// K2: depthwise 3x3 + BN2 + SiLU -> d (bf16) + per-(b,c) mean.
// r11 v2 (strip) version — best measured.
// ---------------------------------------------------------------------------
__global__ __launch_bounds__(256) void k_dw(
    const u16* __restrict__ h, const float* __restrict__ wdw,
    const float* __restrict__ g2, const float* __restrict__ b2,
    const float* __restrict__ m2, const float* __restrict__ v2,
    u16* __restrict__ d, float* __restrict__ mean)
{
  __shared__ float red[4];
  const int tid = threadIdx.x;
  const int c = blockIdx.x, b = blockIdx.y;
  const u32* hp32 = (const u32*)(h + (size_t)(b * HID + c) * HW);

  float wv[9];
  #pragma unroll
  for (int t = 0; t < 9; ++t) wv[t] = wdw[c * 9 + t];
  const float sc = g2[c] * rsqrtf(v2[c] + EPS);
  const float sh = b2[c] - m2[c] * sc;

  float lsum = 0.f;
  if (tid < 224) {
    const int row = tid >> 2, seg = tid & 3;
    const int px0 = seg * 14, w0 = px0 >> 1;

    float v[3][16];
    #pragma unroll
    for (int r3 = 0; r3 < 3; ++r3) {
      int rr = row + r3 - 1;
      bool ok = (rr >= 0) && (rr < 56);
      const u32* rp = hp32 + rr * 28;
      v[r3][0] = (ok && seg > 0) ? bfhi(rp[w0 - 1]) : 0.f;
      #pragma unroll
      for (int t = 0; t < 7; ++t) {
        u32 wd = ok ? rp[w0 + t] : 0u;
        v[r3][1 + 2 * t] = bflo(wd);
        v[r3][2 + 2 * t] = bfhi(wd);
      }
      v[r3][15] = (ok && seg < 3) ? bflo(rp[w0 + 7]) : 0.f;
    }

    u32 pk[7];
    #pragma unroll
    for (int t = 0; t < 7; ++t) {
      float o2[2];
      #pragma unroll
      for (int e = 0; e < 2; ++e) {
        int j = 2 * t + e;
        float s = 0.f;
        #pragma unroll
        for (int r3 = 0; r3 < 3; ++r3)
          #pragma unroll
          for (int dx = 0; dx < 3; ++dx)
            s += v[r3][j + dx] * wv[r3 * 3 + dx];
        float val = fsilu(s * sc + sh);
        lsum += val;
        o2[e] = val;
      }
      pk[t] = (u32)f2b(o2[0]) | ((u32)f2b(o2[1]) << 16);
    }
    u32* dp32 = (u32*)(d + (size_t)(b * HID + c) * HW) + row * 28 + w0;
    #pragma unroll
    for (int t = 0; t < 7; ++t) dp32[t] = pk[t];
  }

  #pragma unroll
  for (int off = 32; off > 0; off >>= 1) lsum += __shfl_down(lsum, off);
  if ((tid & 63) == 0) red[tid >> 6] = lsum;
  __syncthreads();
  if (tid == 0)
    mean[b * HID + c] = (red[0] + red[1] + red[2] + red[3]) * (1.f / 3136.f);
}

// ---------------------------------------------------------------------------
// K3: SE -> sfac only (lightweight). grid bc, block 256.
// ---------------------------------------------------------------------------
__global__ __launch_bounds__(256) void k_se(
    const float* __restrict__ mean, const float* __restrict__ w1,
    const float* __restrict__ w2, float* __restrict__ sfac)
{
  __shared__ float sm[HID];
  __shared__ float ps[16 * 17];
  __shared__ float s1[16];
  const int b = blockIdx.x, tid = threadIdx.x;
  for (int c = tid; c < HID; c += 256) sm[c] = mean[b * HID + c];
  __syncthreads();
  int r = tid >> 4, j = tid & 15;
  float p = 0.f;
  for (int c = j; c < HID; c += 16) p += sm[c] * w1[r * HID + c];
  ps[r * 17 + j] = p;
  __syncthreads();
  if (tid < 16) {
    float s = 0.f;
    #pragma unroll
    for (int q = 0; q < 16; ++q) s += ps[tid * 17 + q];
    s1[tid] = fsilu(s);
  }
  __syncthreads();
  for (int c = tid; c < HID; c += 256) {
    float s = 0.f;
    #pragma unroll
    for (int q = 0; q < 16; ++q) s += s1[q] * w2[c * 16 + q];
    sfac[b * HID + c] = 1.f / (1.f + __expf(-s));
  }
}

// ---------------------------------------------------------------------------
// K4: pointwise MFMA GEMM — A' folded in-kernel from wpw*sfac*sc3 (L2-hot),
// per-wave private B-staging, no K-loop barriers. grid (25, bc), 256 thr.
// ---------------------------------------------------------------------------
constexpr int PWP = 392;

__global__ __launch_bounds__(256, 2) void k_pw_mfma(
    const u16* __restrict__ d, const float* __restrict__ sfac,
    const float* __restrict__ wpw,
    const float* __restrict__ sc3, const float* __restrict__ sh3,
    const float* __restrict__ x, float* __restrict__ out, int b0)
{
  __shared__ u16 sAw[64 * PWP];     // 50,176 B
  __shared__ u32 dtw[4 * 512];      // 8,192 B
  const int tid = threadIdx.x;
  const int b = blockIdx.y, gb = b0 + b;
  const int p0 = blockIdx.x * 128;
  const int wave = tid >> 6, ln = tid & 63;
  const int lane15 = ln & 15, quad = ln >> 4;

  // stage A' with in-kernel fold: 6144 f32x4 chunks of 64x384
  {
    for (int i = tid; i < 6144; i += 256) {
      int e = i * 4, co = e / 384, k = e - co * 384;
      f32x4 wv = *(const f32x4*)&wpw[e];
      f32x4 sf = *(const f32x4*)&sfac[b * HID + k];
      float s3 = sc3[co];
      u32x2 pk;
      pk.x = (u32)f2b(wv.x * sf.x * s3) | ((u32)f2b(wv.y * sf.y * s3) << 16);
      pk.y = (u32)f2b(wv.z * sf.z * s3) | ((u32)f2b(wv.w * sf.w * s3) << 16);
      *(u32x2*)&sAw[co * PWP + k] = pk;
    }
  }
  __syncthreads();

  f32x4 acc[4][2];
  #pragma unroll
  for (int ms = 0; ms < 4; ++ms)
    #pragma unroll
    for (int ns = 0; ns < 2; ++ns) acc[ms][ns] = (f32x4){0.f, 0.f, 0.f, 0.f};

  const int cpair = ln >> 2;
  const int pxo = (ln & 3) * 8;
  const int pbase = p0 + wave * 32;
  u32* mydt = &dtw[wave * 512];
  const bool ld_ok = (pbase + pxo + 8 <= HW);

  for (int ks = 0; ks < 12; ++ks) {
    const int k0 = ks * 32;
    u32x4 r0 = {0,0,0,0}, r1 = {0,0,0,0};
    if (ld_ok) {
      int c = k0 + 2 * cpair;
      const u16* dpp = d + (size_t)(b * HID + c) * HW + pbase + pxo;
      r0 = *(const u32x4*)dpp;
      r1 = *(const u32x4*)(dpp + HW);
    }
    u32* w0 = &mydt[pxo * 16 + cpair];
    w0[0 * 16] = (r0.x & 0xffffu) | (r1.x << 16);
    w0[1 * 16] = (r0.x >> 16)     | (r1.x & 0xffff0000u);
    w0[2 * 16] = (r0.y & 0xffffu) | (r1.y << 16);
    w0[3 * 16] = (r0.y >> 16)     | (r1.y & 0xffff0000u);
    w0[4 * 16] = (r0.z & 0xffffu) | (r1.z << 16);
    w0[5 * 16] = (r0.z >> 16)     | (r1.z & 0xffff0000u);
    w0[6 * 16] = (r0.w & 0xffffu) | (r1.w << 16);
    w0[7 * 16] = (r0.w >> 16)     | (r1.w & 0xffff0000u);
    s16x8 af[4], bf[2];
    #pragma unroll
    for (int ms = 0; ms < 4; ++ms) {
      int ocl = ms * 16 + lane15;
      af[ms] = *(const s16x8*)&sAw[ocl * PWP + k0 + quad * 8];
    }
    #pragma unroll
    for (int ns = 0; ns < 2; ++ns) {
      int pxl = ns * 16 + lane15;
      bf[ns] = *(const s16x8*)((const u16*)mydt + pxl * 32 + quad * 8);
    }
    #pragma unroll
    for (int ms = 0; ms < 4; ++ms)
      #pragma unroll
      for (int ns = 0; ns < 2; ++ns)
        acc[ms][ns] = __builtin_amdgcn_mfma_f32_16x16x32_bf16(
            af[ms], bf[ns], acc[ms][ns], 0, 0, 0);
  }

  #pragma unroll
  for (int ns = 0; ns < 2; ++ns) {
    int p = pbase + ns * 16 + lane15;
    if (p < HW) {
      #pragma unroll
      for (int ms = 0; ms < 4; ++ms) {
        int co0 = ms * 16 + quad * 4;
        float av[4] = {acc[ms][ns].x, acc[ms][ns].y, acc[ms][ns].z, acc[ms][ns].w};
        #pragma unroll
        for (int r = 0; r < 4; ++r) {
          size_t idx = (size_t)(gb * CO + co0 + r) * HW + p;
          out[idx] = av[r] + sh3[co0 + r] + x[idx];
        }
      }
    }
  }
}

// ---------------------------------------------------------------------------
extern "C" void kernel_launch(void* const* d_in, const int* in_sizes, int n_in,
                              void* d_out, int out_size, void* d_ws, size_t ws_size,
                              hipStream_t stream)
{
  (void)in_sizes; (void)n_in; (void)out_size;
  const float* x     = (const float*)d_in[0];
  const float* w_exp = (const float*)d_in[1];
  const float* g1 = (const float*)d_in[2];
  const float* b1 = (const float*)d_in[3];
  const float* m1 = (const float*)d_in[4];
  const float* v1 = (const float*)d_in[5];
  const float* w_dw = (const float*)d_in[6];
  const float* g2 = (const float*)d_in[7];
  const float* b2 = (const float*)d_in[8];
  const float* m2 = (const float*)d_in[9];
  const float* v2 = (const float*)d_in[10];
  const float* w_se1 = (const float*)d_in[11];
  const float* w_se2 = (const float*)d_in[12];
  const float* w_pw  = (const float*)d_in[13];
  const float* g3 = (const float*)d_in[14];
  const float* b3 = (const float*)d_in[15];
  const float* m3 = (const float*)d_in[16];
  const float* v3 = (const float*)d_in[17];

  const size_t perB = (size_t)HID * HW * 2 * 2 + HID * 8;   // h + d + mean+sfac
  const size_t fixed = 221184 * 2 + HID * 8 + CO * 8;
  int bc = Bn;
  while (bc > 1 && fixed + (size_t)bc * perB > ws_size) bc >>= 1;

  u16* wt = (u16*)d_ws;
  float* sc1 = (float*)(wt + 221184);
  float* sh1 = sc1 + HID;
  float* sc3 = sh1 + HID;
  float* sh3 = sc3 + CO;
  u16* h  = (u16*)(sh3 + CO);
  u16* dd = h + (size_t)bc * HID * HW;
  float* mean = (float*)(dd + (size_t)bc * HID * HW);
  float* sfac = mean + (size_t)bc * HID;

  k_prep_wbn<<<865, 256, 0, stream>>>(w_exp, g1, b1, m1, v1, g3, b3, m3, v3,
                                      wt, sc1, sh1, sc3, sh3);

  for (int b0 = 0; b0 < Bn; b0 += bc) {
    k_expand_mfma<<<dim3(28, bc), 256, 0, stream>>>(x, wt, sc1, sh1, h, b0);
    k_dw<<<dim3(HID, bc), 256, 0, stream>>>(h, w_dw, g2, b2, m2, v2, dd, mean);
    k_se<<<bc, 256, 0, stream>>>(mean, w_se1, w_se2, sfac);
    k_pw_mfma<<<dim3(25, bc), 256, 0, stream>>>(dd, sfac, w_pw, sc3, sh3,
                                                x, (float*)d_out, b0);
  }
}

// Round 14
// 279.467 us; speedup vs baseline: 1.1471x; 1.0317x over previous
//
#include <hip/hip_runtime.h>

typedef unsigned short u16;
typedef unsigned int u32;
typedef __attribute__((ext_vector_type(2))) u32 u32x2;
typedef __attribute__((ext_vector_type(4))) u32 u32x4;
typedef __attribute__((ext_vector_type(4))) float f32x4;
typedef __attribute__((ext_vector_type(8))) short s16x8;

#define DEV __device__ __forceinline__

DEV float bflo(u32 u){ union{u32 i; float f;} c; c.i = u << 16; return c.f; }
DEV float bfhi(u32 u){ union{u32 i; float f;} c; c.i = u & 0xffff0000u; return c.f; }
DEV u16 f2b(float f){
  union{float f; u32 u;} c; c.f = f;
  u32 u = c.u;
  u32 r = (u + 0x7fffu + ((u >> 16) & 1u)) >> 16;
  return (u16)r;
}
DEV float fsilu(float v){ return v / (1.f + __expf(-v)); }

constexpr int Bn = 32, Cin = 64, H = 56, Wd = 56, HID = 384, CO = 64;
constexpr int HW = H * Wd;            // 3136
constexpr float EPS = 1e-5f;

constexpr int XROW = 72 * 64;         // sB row pitch: [slot 72][ic 64] bf16
constexpr int WTAP = 128 * 64;
constexpr int WOCT = 9 * WTAP;

// ---------------------------------------------------------------------------
// P1: pack expand weights -> wt (swizzled) + BN1/BN3 scale-shift (block 864).
// ---------------------------------------------------------------------------
__global__ __launch_bounds__(256) void k_prep_wbn(
    const float* __restrict__ w,
    const float* __restrict__ g1, const float* __restrict__ b1,
    const float* __restrict__ m1, const float* __restrict__ v1,
    const float* __restrict__ g3, const float* __restrict__ b3,
    const float* __restrict__ m3, const float* __restrict__ v3,
    u16* __restrict__ wt,
    float* __restrict__ sc1, float* __restrict__ sh1,
    float* __restrict__ sc3, float* __restrict__ sh3)
{
  const int blk = blockIdx.x;
  if (blk < 864) {
    int t = blk * 256 + threadIdx.x;
    int octile = t / WOCT, r = t - octile * WOCT;
    int tap = r / WTAP, r2 = r - tap * WTAP;
    int ocl = r2 >> 6, col = r2 & 63;
    int physo = col >> 3, j = col & 7;
    int olog = physo ^ (ocl & 7);
    int ic = olog * 8 + j;
    int oc = octile * 128 + ocl;
    wt[t] = f2b(w[(oc * Cin + ic) * 9 + tap]);
  } else {
    for (int t = threadIdx.x; t < HID; t += 256) {
      float sc = g1[t] * rsqrtf(v1[t] + EPS);
      sc1[t] = sc;
      sh1[t] = b1[t] - m1[t] * sc;
    }
    if (threadIdx.x < CO) {
      int t = threadIdx.x;
      float sc = g3[t] * rsqrtf(v3[t] + EPS);
      sc3[t] = sc;
      sh3[t] = b3[t] - m3[t] * sc;
    }
  }
}

// ---------------------------------------------------------------------------
// K1: expand conv MFMA shift-GEMM (r12/r13 merged version — unchanged).
// ---------------------------------------------------------------------------
__global__ __launch_bounds__(256, 2) void k_expand_mfma(
    const float* __restrict__ x, const u16* __restrict__ wt,
    const float* __restrict__ sc1, const float* __restrict__ sh1,
    u16* __restrict__ h, int b0)
{
  __shared__ u16 sB[4 * XROW];
  __shared__ u16 sA[WTAP];
  const int tid = threadIdx.x;
  const int ypair = blockIdx.x, b = blockIdx.y;
  const int gb = b0 + b;
  const int y0 = ypair * 2;
  const int wave = tid >> 6, ln = tid & 63;
  const int wm = wave >> 1, wn = wave & 1;
  const int lane15 = ln & 15, quad = ln >> 4;

  {
    u32x4 z = {0, 0, 0, 0};
    #pragma unroll
    for (int i = 0; i < 18; ++i)
      *(u32x4*)&sB[(i * 256 + tid) * 8] = z;
  }
  __syncthreads();
  {
    const int ic = tid & 63, xq = tid >> 6;
    #pragma unroll
    for (int r = 0; r < 4; ++r) {
      const int y = y0 + r - 1;
      if (y >= 0 && y < H) {
        const float* xp = x + ((size_t)(gb * Cin + ic) * H + y) * Wd + xq * 14;
        float vals[14];
        #pragma unroll
        for (int t = 0; t < 14; ++t) vals[t] = xp[t];
        u16* rowp = &sB[r * XROW];
        #pragma unroll
        for (int t = 0; t < 14; ++t) {
          int slot = xq * 14 + t + 1;
          int pos = slot * 64 + (((ic >> 3) ^ (slot & 7)) << 3) + (ic & 7);
          rowp[pos] = f2b(vals[t]);
        }
      }
    }
  }

  const int y = y0 + wn;

  for (int octile = 0; octile < 3; ++octile) {
    f32x4 acc[4][4];
    #pragma unroll
    for (int ms = 0; ms < 4; ++ms)
      #pragma unroll
      for (int ns = 0; ns < 4; ++ns) acc[ms][ns] = (f32x4){0.f, 0.f, 0.f, 0.f};

    const u16* wsrc = wt + (size_t)octile * WOCT;
    for (int tap = 0; tap < 9; ++tap) {
      __syncthreads();
      #pragma unroll
      for (int it = 0; it < 4; ++it) {
        int i = it * 256 + tid;
        *(u32x4*)&sA[i * 8] = *(const u32x4*)&wsrc[tap * WTAP + i * 8];
      }
      __syncthreads();
      const int dy = tap / 3, dx = tap - dy * 3;
      #pragma unroll
      for (int kk = 0; kk < 2; ++kk) {
        s16x8 af[4], bf[4];
        #pragma unroll
        for (int ms = 0; ms < 4; ++ms) {
          int ocl = wm * 64 + ms * 16 + lane15;
          int po = (kk * 4 + quad) ^ (ocl & 7);
          af[ms] = *(const s16x8*)&sA[ocl * 64 + po * 8];
        }
        #pragma unroll
        for (int ns = 0; ns < 4; ++ns) {
          int row = wn + dy;
          int slot = ns * 16 + lane15 + dx;
          int po = (kk * 4 + quad) ^ (slot & 7);
          bf[ns] = *(const s16x8*)&sB[(row * 72 + slot) * 64 + po * 8];
        }
        #pragma unroll
        for (int ms = 0; ms < 4; ++ms)
          #pragma unroll
          for (int ns = 0; ns < 4; ++ns)
            acc[ms][ns] = __builtin_amdgcn_mfma_f32_16x16x32_bf16(
                af[ms], bf[ns], acc[ms][ns], 0, 0, 0);
      }
    }

    #pragma unroll
    for (int ms = 0; ms < 4; ++ms) {
      int oc0 = octile * 128 + wm * 64 + ms * 16 + quad * 4;
      f32x4 sc = *(const f32x4*)&sc1[oc0];
      f32x4 sh = *(const f32x4*)&sh1[oc0];
      float scr[4] = {sc.x, sc.y, sc.z, sc.w};
      float shr[4] = {sh.x, sh.y, sh.z, sh.w};
      #pragma unroll
      for (int ns = 0; ns < 4; ++ns) {
        int xg = ns * 16 + lane15;
        if (xg < Wd) {
          float av[4] = {acc[ms][ns].x, acc[ms][ns].y, acc[ms][ns].z, acc[ms][ns].w};
          #pragma unroll
          for (int r = 0; r < 4; ++r) {
            float val = fsilu(av[r] * scr[r] + shr[r]);
            h[((size_t)(b * HID + oc0 + r) * H + y) * Wd + xg] = f2b(val);
          }
        }
      }
    }
  }
}

// ---------------------------------------------------------------------------
// K2: depthwise 3x3 + BN2 + SiLU -> d (bf16) + per-(b,c) mean (r11 v2).
// ---------------------------------------------------------------------------
__global__ __launch_bounds__(256) void k_dw(
    const u16* __restrict__ h, const float* __restrict__ wdw,
    const float* __restrict__ g2, const float* __restrict__ b2,
    const float* __restrict__ m2, const float* __restrict__ v2,
    u16* __restrict__ d, float* __restrict__ mean)
{
  __shared__ float red[4];
  const int tid = threadIdx.x;
  const int c = blockIdx.x, b = blockIdx.y;
  const u32* hp32 = (const u32*)(h + (size_t)(b * HID + c) * HW);

  float wv[9];
  #pragma unroll
  for (int t = 0; t < 9; ++t) wv[t] = wdw[c * 9 + t];
  const float sc = g2[c] * rsqrtf(v2[c] + EPS);
  const float sh = b2[c] - m2[c] * sc;

  float lsum = 0.f;
  if (tid < 224) {
    const int row = tid >> 2, seg = tid & 3;
    const int px0 = seg * 14, w0 = px0 >> 1;

    float v[3][16];
    #pragma unroll
    for (int r3 = 0; r3 < 3; ++r3) {
      int rr = row + r3 - 1;
      bool ok = (rr >= 0) && (rr < 56);
      const u32* rp = hp32 + rr * 28;
      v[r3][0] = (ok && seg > 0) ? bfhi(rp[w0 - 1]) : 0.f;
      #pragma unroll
      for (int t = 0; t < 7; ++t) {
        u32 wd = ok ? rp[w0 + t] : 0u;
        v[r3][1 + 2 * t] = bflo(wd);
        v[r3][2 + 2 * t] = bfhi(wd);
      }
      v[r3][15] = (ok && seg < 3) ? bflo(rp[w0 + 7]) : 0.f;
    }

    u32 pk[7];
    #pragma unroll
    for (int t = 0; t < 7; ++t) {
      float o2[2];
      #pragma unroll
      for (int e = 0; e < 2; ++e) {
        int j = 2 * t + e;
        float s = 0.f;
        #pragma unroll
        for (int r3 = 0; r3 < 3; ++r3)
          #pragma unroll
          for (int dx = 0; dx < 3; ++dx)
            s += v[r3][j + dx] * wv[r3 * 3 + dx];
        float val = fsilu(s * sc + sh);
        lsum += val;
        o2[e] = val;
      }
      pk[t] = (u32)f2b(o2[0]) | ((u32)f2b(o2[1]) << 16);
    }
    u32* dp32 = (u32*)(d + (size_t)(b * HID + c) * HW) + row * 28 + w0;
    #pragma unroll
    for (int t = 0; t < 7; ++t) dp32[t] = pk[t];
  }

  #pragma unroll
  for (int off = 32; off > 0; off >>= 1) lsum += __shfl_down(lsum, off);
  if ((tid & 63) == 0) red[tid >> 6] = lsum;
  __syncthreads();
  if (tid == 0)
    mean[b * HID + c] = (red[0] + red[1] + red[2] + red[3]) * (1.f / 3136.f);
}

// ---------------------------------------------------------------------------
// K3: SE -> sfac only. grid bc, block 256.
// ---------------------------------------------------------------------------
__global__ __launch_bounds__(256) void k_se(
    const float* __restrict__ mean, const float* __restrict__ w1,
    const float* __restrict__ w2, float* __restrict__ sfac)
{
  __shared__ float sm[HID];
  __shared__ float ps[16 * 17];
  __shared__ float s1[16];
  const int b = blockIdx.x, tid = threadIdx.x;
  for (int c = tid; c < HID; c += 256) sm[c] = mean[b * HID + c];
  __syncthreads();
  int r = tid >> 4, j = tid & 15;
  float p = 0.f;
  for (int c = j; c < HID; c += 16) p += sm[c] * w1[r * HID + c];
  ps[r * 17 + j] = p;
  __syncthreads();
  if (tid < 16) {
    float s = 0.f;
    #pragma unroll
    for (int q = 0; q < 16; ++q) s += ps[tid * 17 + q];
    s1[tid] = fsilu(s);
  }
  __syncthreads();
  for (int c = tid; c < HID; c += 256) {
    float s = 0.f;
    #pragma unroll
    for (int q = 0; q < 16; ++q) s += s1[q] * w2[c * 16 + q];
    sfac[b * HID + c] = 1.f / (1.f + __expf(-s));
  }
}

// ---------------------------------------------------------------------------
// K4: pointwise MFMA GEMM v4 — 256-px tiles, wave = 64 px x 64 co
// (16 MFMA/K-step), register-prefetched d-loads, no K-loop barriers,
// XOR-swizzled dt for <=4-way write conflicts. grid (13, bc), 256 thr.
// ---------------------------------------------------------------------------
constexpr int PWP = 392;

__global__ __launch_bounds__(256, 2) void k_pw_mfma(
    const u16* __restrict__ d, const float* __restrict__ sfac,
    const float* __restrict__ wpw,
    const float* __restrict__ sc3, const float* __restrict__ sh3,
    const float* __restrict__ x, float* __restrict__ out, int b0)
{
  __shared__ u16 sAw[64 * PWP];     // 50,176 B
  __shared__ u32 dtw[4 * 1024];     // 16,384 B : per-wave 64px x 16 k-pairs
  const int tid = threadIdx.x;
  const int b = blockIdx.y, gb = b0 + b;
  const int p0 = blockIdx.x * 256;
  const int wave = tid >> 6, ln = tid & 63;
  const int lane15 = ln & 15, quad = ln >> 4;

  // stage A' with in-kernel fold
  {
    for (int i = tid; i < 6144; i += 256) {
      int e = i * 4, co = e / 384, k = e - co * 384;
      f32x4 wv = *(const f32x4*)&wpw[e];
      f32x4 sf = *(const f32x4*)&sfac[b * HID + k];
      float s3 = sc3[co];
      u32x2 pk;
      pk.x = (u32)f2b(wv.x * sf.x * s3) | ((u32)f2b(wv.y * sf.y * s3) << 16);
      pk.y = (u32)f2b(wv.z * sf.z * s3) | ((u32)f2b(wv.w * sf.w * s3) << 16);
      *(u32x2*)&sAw[co * PWP + k] = pk;
    }
  }
  __syncthreads();

  f32x4 acc[4][4];
  #pragma unroll
  for (int ms = 0; ms < 4; ++ms)
    #pragma unroll
    for (int ns = 0; ns < 4; ++ns) acc[ms][ns] = (f32x4){0.f, 0.f, 0.f, 0.f};

  const int cpair8 = ln >> 3;          // 0..7
  const int pxo = (ln & 7) * 8;        // 0..56 (wave-local px octet)
  const int swz = ln & 3;              // = (px>>3)&3 for this lane's pxo
  const int pbase = p0 + wave * 64;
  u32* mydt = &dtw[wave * 1024];
  const bool ld_ok = (pbase + pxo + 8 <= HW);
  const u16* dbase = d + (size_t)b * HID * HW + pbase + pxo;

  // prefetch ks=0
  u32x4 pr0[2], pr1[2];
  #pragma unroll
  for (int ci = 0; ci < 2; ++ci) {
    pr0[ci] = (u32x4){0,0,0,0}; pr1[ci] = (u32x4){0,0,0,0};
    if (ld_ok) {
      int c = 2 * (ci * 8 + cpair8);
      const u16* dpp = dbase + (size_t)c * HW;
      pr0[ci] = *(const u32x4*)dpp;
      pr1[ci] = *(const u32x4*)(dpp + HW);
    }
  }

  for (int ks = 0; ks < 12; ++ks) {
    // write current prefetched B-tile to LDS
    #pragma unroll
    for (int ci = 0; ci < 2; ++ci) {
      int k4 = ci * 2 + (cpair8 >> 2);
      u32* w0 = &mydt[pxo * 16 + ((k4 ^ swz) << 2) + (cpair8 & 3)];
      u32x4 r0 = pr0[ci], r1 = pr1[ci];
      w0[0 * 16] = (r0.x & 0xffffu) | (r1.x << 16);
      w0[1 * 16] = (r0.x >> 16)     | (r1.x & 0xffff0000u);
      w0[2 * 16] = (r0.y & 0xffffu) | (r1.y << 16);
      w0[3 * 16] = (r0.y >> 16)     | (r1.y & 0xffff0000u);
      w0[4 * 16] = (r0.z & 0xffffu) | (r1.z << 16);
      w0[5 * 16] = (r0.z >> 16)     | (r1.z & 0xffff0000u);
      w0[6 * 16] = (r0.w & 0xffffu) | (r1.w << 16);
      w0[7 * 16] = (r0.w >> 16)     | (r1.w & 0xffff0000u);
    }
    // prefetch next ks (in flight during LDS reads + MFMAs)
    if (ks < 11) {
      #pragma unroll
      for (int ci = 0; ci < 2; ++ci) {
        if (ld_ok) {
          int c = (ks + 1) * 32 + 2 * (ci * 8 + cpair8);
          const u16* dpp = dbase + (size_t)c * HW;
          pr0[ci] = *(const u32x4*)dpp;
          pr1[ci] = *(const u32x4*)(dpp + HW);
        }
      }
    }
    // LDS reads + MFMA (same-wave ordering; no barrier)
    const int k0 = ks * 32;
    s16x8 af[4], bf[4];
    #pragma unroll
    for (int ms = 0; ms < 4; ++ms) {
      int ocl = ms * 16 + lane15;
      af[ms] = *(const s16x8*)&sAw[ocl * PWP + k0 + quad * 8];
    }
    #pragma unroll
    for (int ns = 0; ns < 4; ++ns) {
      int pxl = ns * 16 + lane15;
      int p4 = quad ^ ((pxl >> 3) & 3);
      bf[ns] = *(const s16x8*)((const u16*)mydt + pxl * 32 + p4 * 8);
    }
    #pragma unroll
    for (int ms = 0; ms < 4; ++ms)
      #pragma unroll
      for (int ns = 0; ns < 4; ++ns)
        acc[ms][ns] = __builtin_amdgcn_mfma_f32_16x16x32_bf16(
            af[ms], bf[ns], acc[ms][ns], 0, 0, 0);
  }

  #pragma unroll
  for (int ns = 0; ns < 4; ++ns) {
    int p = pbase + ns * 16 + lane15;
    if (p < HW) {
      #pragma unroll
      for (int ms = 0; ms < 4; ++ms) {
        int co0 = ms * 16 + quad * 4;
        float av[4] = {acc[ms][ns].x, acc[ms][ns].y, acc[ms][ns].z, acc[ms][ns].w};
        #pragma unroll
        for (int r = 0; r < 4; ++r) {
          size_t idx = (size_t)(gb * CO + co0 + r) * HW + p;
          out[idx] = av[r] + sh3[co0 + r] + x[idx];
        }
      }
    }
  }
}

// ---------------------------------------------------------------------------
extern "C" void kernel_launch(void* const* d_in, const int* in_sizes, int n_in,
                              void* d_out, int out_size, void* d_ws, size_t ws_size,
                              hipStream_t stream)
{
  (void)in_sizes; (void)n_in; (void)out_size;
  const float* x     = (const float*)d_in[0];
  const float* w_exp = (const float*)d_in[1];
  const float* g1 = (const float*)d_in[2];
  const float* b1 = (const float*)d_in[3];
  const float* m1 = (const float*)d_in[4];
  const float* v1 = (const float*)d_in[5];
  const float* w_dw = (const float*)d_in[6];
  const float* g2 = (const float*)d_in[7];
  const float* b2 = (const float*)d_in[8];
  const float* m2 = (const float*)d_in[9];
  const float* v2 = (const float*)d_in[10];
  const float* w_se1 = (const float*)d_in[11];
  const float* w_se2 = (const float*)d_in[12];
  const float* w_pw  = (const float*)d_in[13];
  const float* g3 = (const float*)d_in[14];
  const float* b3 = (const float*)d_in[15];
  const float* m3 = (const float*)d_in[16];
  const float* v3 = (const float*)d_in[17];

  const size_t perB = (size_t)HID * HW * 2 * 2 + HID * 8;
  const size_t fixed = 221184 * 2 + HID * 8 + CO * 8;
  int bc = Bn;
  while (bc > 1 && fixed + (size_t)bc * perB > ws_size) bc >>= 1;

  u16* wt = (u16*)d_ws;
  float* sc1 = (float*)(wt + 221184);
  float* sh1 = sc1 + HID;
  float* sc3 = sh1 + HID;
  float* sh3 = sc3 + CO;
  u16* h  = (u16*)(sh3 + CO);
  u16* dd = h + (size_t)bc * HID * HW;
  float* mean = (float*)(dd + (size_t)bc * HID * HW);
  float* sfac = mean + (size_t)bc * HID;

  k_prep_wbn<<<865, 256, 0, stream>>>(w_exp, g1, b1, m1, v1, g3, b3, m3, v3,
                                      wt, sc1, sh1, sc3, sh3);

  for (int b0 = 0; b0 < Bn; b0 += bc) {
    k_expand_mfma<<<dim3(28, bc), 256, 0, stream>>>(x, wt, sc1, sh1, h, b0);
    k_dw<<<dim3(HID, bc), 256, 0, stream>>>(h, w_dw, g2, b2, m2, v2, dd, mean);
    k_se<<<bc, 256, 0, stream>>>(mean, w_se1, w_se2, sfac);
    k_pw_mfma<<<dim3(13, bc), 256, 0, stream>>>(dd, sfac, w_pw, sc3, sh3,
                                                x, (float*)d_out, b0);
  }
}